// Round 3
// baseline (480.620 us; speedup 1.0000x reference)
//
#include <hip/hip_runtime.h>

#define P_TOT 1482625
#define BATCH 64
#define EMB 16
#define DFEAT 512
#define KCODE 512

// ---------------------------------------------------------------------------
// Kernel 1: encoder fc + VQ argmin + quantized + per-batch loss partial (fp32).
// grid = 64 blocks (one per batch row), 256 threads.  (~3 us, off critical path)
// ---------------------------------------------------------------------------
__global__ __launch_bounds__(256) void k_embed_vq(
    const float* __restrict__ feat,
    const float* __restrict__ fcw,
    const float* __restrict__ fcb,
    const float* __restrict__ cb,
    float* __restrict__ qws,
    float* __restrict__ loss_part)
{
    const int b   = blockIdx.x;
    const int tid = threadIdx.x;

    __shared__ float red[EMB][17];
    __shared__ float embed_s[EMB];
    __shared__ float dist_s[256];
    __shared__ int   idx_s[256];

    {
        const int e = tid >> 4;       // 0..15
        const int c = tid & 15;       // chunk of 32 floats
        const float4* fp = (const float4*)(feat + b * DFEAT + c * 32);
        const float4* wp = (const float4*)(fcw  + e * DFEAT + c * 32);
        float acc = 0.f;
#pragma unroll
        for (int j = 0; j < 8; j++) {
            float4 f = fp[j], w = wp[j];
            acc += f.x * w.x + f.y * w.y + f.z * w.z + f.w * w.w;
        }
        red[e][c] = acc;
    }
    __syncthreads();
    if (tid < EMB) {
        float s = fcb[tid];
#pragma unroll
        for (int c = 0; c < 16; c++) s += red[tid][c];
        embed_s[tid] = s;
    }
    __syncthreads();

    float emb[EMB];
#pragma unroll
    for (int e = 0; e < EMB; e++) emb[e] = embed_s[e];

    float bestd = 1e30f;
    int   bestk = 0;
#pragma unroll
    for (int r = 0; r < 2; r++) {
        const int k = tid + r * 256;
        const float4* cp = (const float4*)(cb + k * EMB);
        float d = 0.f;
#pragma unroll
        for (int q = 0; q < 4; q++) {
            float4 cv = cp[q];
            d += cv.x * cv.x - 2.f * cv.x * emb[q * 4 + 0];
            d += cv.y * cv.y - 2.f * cv.y * emb[q * 4 + 1];
            d += cv.z * cv.z - 2.f * cv.z * emb[q * 4 + 2];
            d += cv.w * cv.w - 2.f * cv.w * emb[q * 4 + 3];
        }
        if (d < bestd) { bestd = d; bestk = k; }  // strict < => first-min kept
    }
    dist_s[tid] = bestd;
    idx_s[tid]  = bestk;
    __syncthreads();

    for (int s = 128; s > 0; s >>= 1) {
        if (tid < s) {
            float od = dist_s[tid + s];
            int   ok = idx_s[tid + s];
            if (od < dist_s[tid] || (od == dist_s[tid] && ok < idx_s[tid])) {
                dist_s[tid] = od;
                idx_s[tid]  = ok;
            }
        }
        __syncthreads();
    }

    if (tid == 0) {
        const int kb = idx_s[0];
        float l = 0.f;
#pragma unroll
        for (int e = 0; e < EMB; e++) {
            float qv = cb[kb * EMB + e];
            qws[b * EMB + e] = qv;        // forward(quantized_st) == quantized
            float dd = qv - embed_s[e];
            l += dd * dd;
        }
        loss_part[b] = l;
    }
}

// ---------------------------------------------------------------------------
// Kernel 2: gen = quantized @ Wgen ([64,16]x[16,P]) + loss finalize (fp32).
// THEORY (r3): k_gen (~229us, 2.1 TB/s vs 6.3 achievable) is store-ACK-
// latency bound: vmcnt for stores decrements on L2 write-ack (~200-400cy);
// with unroll-2 the acc registers are reused after only ~256cy of FMA, so
// the compiler's s_waitcnt before each reuse exposes the ACK tail every
// iteration. (Also explains round-1's regression: 2-col threads halved the
// reuse distance.)
// FIX: group 4 b-iterations — compute acc[4][4] (16 regs), then issue all
// 16 stores; register reuse now happens a full group (~640cy of FMA) after
// issue. q read directly via s_load (wave-uniform -> SGPRs, saves 32 VGPR,
// keeps us <=128 -> 4 waves/SIMD).
// ---------------------------------------------------------------------------
__global__ __launch_bounds__(256) void k_gen(
    const float* __restrict__ Wgen,
    const float* __restrict__ qws,
    const float* __restrict__ loss_part,
    float* __restrict__ out)
{
    if (blockIdx.x == 0) {
        if (threadIdx.x < 64) {
            float v = loss_part[threadIdx.x];
#pragma unroll
            for (int o = 32; o > 0; o >>= 1) v += __shfl_down(v, o, 64);
            if (threadIdx.x == 0)
                out[(size_t)BATCH * P_TOT] = 1.25f * v * (1.0f / 1024.0f);
        }
        return;
    }

    const int lane = threadIdx.x & 63;
    const int wv   = threadIdx.x >> 6;
    const int myc  = wv * 256 + lane;                 // + j*64, j<4
    const size_t col0 = (size_t)(blockIdx.x - 1) * 1024;

    if (col0 + 1024 <= (size_t)P_TOT) {
        // full block: no bounds checks
        const float* wp = Wgen + col0 + myc;
        float w[EMB][4];
#pragma unroll
        for (int e = 0; e < EMB; e++) {
            const float* we = wp + (size_t)e * P_TOT;
#pragma unroll
            for (int j = 0; j < 4; j++) w[e][j] = we[j * 64];
        }

        float* op = out + col0 + myc;
        for (int b0 = 0; b0 < BATCH; b0 += 4) {
            float acc[4][4];
            // compute phase: 4 rows x 4 cols, 256 FMAs, no stores
#pragma unroll
            for (int u = 0; u < 4; u++) {
                const float* q = qws + (b0 + u) * EMB;   // uniform -> s_load
#pragma unroll
                for (int j = 0; j < 4; j++) acc[u][j] = 0.f;
#pragma unroll
                for (int e = 0; e < EMB; e++) {
                    const float qe = q[e];
#pragma unroll
                    for (int j = 0; j < 4; j++)
                        acc[u][j] = fmaf(qe, w[e][j], acc[u][j]);
                }
            }
            // store phase: 16 stores issued as a burst; their registers are
            // not reused until the NEXT group's compute phase completes.
#pragma unroll
            for (int u = 0; u < 4; u++) {
                float* ob = op + (size_t)(b0 + u) * P_TOT;
#pragma unroll
                for (int j = 0; j < 4; j++) ob[j * 64] = acc[u][j];
            }
        }
    } else {
        // tail block: per-column guard
#pragma unroll
        for (int j = 0; j < 4; j++) {
            const size_t c = col0 + myc + (size_t)j * 64;
            if (c < (size_t)P_TOT) {
                float w1[EMB];
#pragma unroll
                for (int e = 0; e < EMB; e++)
                    w1[e] = Wgen[(size_t)e * P_TOT + c];
                for (int b = 0; b < BATCH; b++) {
                    const float* q = qws + b * EMB;
                    float a = 0.f;
#pragma unroll
                    for (int e = 0; e < EMB; e++) a = fmaf(q[e], w1[e], a);
                    out[(size_t)b * P_TOT + c] = a;
                }
            }
        }
    }
}

extern "C" void kernel_launch(void* const* d_in, const int* in_sizes, int n_in,
                              void* d_out, int out_size, void* d_ws, size_t ws_size,
                              hipStream_t stream) {
    const float* feat = (const float*)d_in[0];
    const float* fcw  = (const float*)d_in[1];
    const float* fcb  = (const float*)d_in[2];
    const float* cb   = (const float*)d_in[3];
    const float* wgen = (const float*)d_in[4];
    float* out = (float*)d_out;

    float* qws   = (float*)d_ws;          // 1024 fp32
    float* lpart = qws + BATCH * EMB;     // 64 fp32

    k_embed_vq<<<BATCH, 256, 0, stream>>>(feat, fcw, fcb, cb, qws, lpart);

    const int colblocks = (P_TOT + 1023) / 1024;      // 1448
    k_gen<<<colblocks + 1, 256, 0, stream>>>(wgen, qws, lpart, out);
}